// Round 21
// baseline (94.225 us; speedup 1.0000x reference)
//
#include <hip/hip_runtime.h>

#define NB 64
#define NCHUNK 8
#define ZINV 0.125f
#define LOG2E 1.44269504088896f
#define EPS 1e-5f

typedef __attribute__((ext_vector_type(8))) short short8;
typedef __attribute__((ext_vector_type(4))) float f32x4;
typedef unsigned short ushort_t;

__device__ __forceinline__ f32x4 mm(short8 a, short8 b, f32x4 c) {
  return __builtin_amdgcn_mfma_f32_16x16x32_bf16(a, b, c, 0, 0, 0);
}
__device__ __forceinline__ ushort_t f2bf(float f) {
  unsigned u = __float_as_uint(f);
  u += 0x7fffu + ((u >> 16) & 1u);
  return (ushort_t)(u >> 16);
}
__device__ __forceinline__ unsigned pack2(float a, float b) {
  return (unsigned)f2bf(a) | ((unsigned)f2bf(b) << 16);
}
// 8 fp32 (two float4) -> short8 bf16 frag
__device__ __forceinline__ short8 cvt8(float4 a, float4 b) {
  union { unsigned u[4]; short8 s; } z;
  z.u[0] = pack2(a.x, a.y); z.u[1] = pack2(a.z, a.w);
  z.u[2] = pack2(b.x, b.y); z.u[3] = pack2(b.z, b.w);
  return z.s;
}
// convert 16 contiguous f32 -> 16 contiguous bf16 (both 16B-aligned)
__device__ __forceinline__ void cvt16(const float* __restrict__ src, ushort_t* dst) {
  const float4* s = (const float4*)src;
  unsigned* d = (unsigned*)dst;
  float4 A0 = s[0], A1 = s[1], A2 = s[2], A3 = s[3];
  d[0] = pack2(A0.x, A0.y); d[1] = pack2(A0.z, A0.w);
  d[2] = pack2(A1.x, A1.y); d[3] = pack2(A1.z, A1.w);
  d[4] = pack2(A2.x, A2.y); d[5] = pack2(A2.z, A2.w);
  d[6] = pack2(A3.x, A3.y); d[7] = pack2(A3.z, A3.w);
}

// ---------------------------------------------------------------------------
// Setup (1 block): offsets + tile-offset prefix (wave-scan); tmap filled
// COOPERATIVELY by all 256 threads (coalesced); bf16 weight tables; QK0 via
// 2 MFMAs. QK0bf carries ZINV*LOG2E (phases use exp2).
// ---------------------------------------------------------------------------
__global__ __launch_bounds__(256) void k_setup(const int* __restrict__ xlens,
                                               const float* __restrict__ I,
                                               const float* __restrict__ WQ0,
                                               const float* __restrict__ WK0,
                                               const float* __restrict__ FCw1,
                                               const float* __restrict__ WV0,
                                               const float* __restrict__ FCw0,
                                               const float* __restrict__ WK1,
                                               const float* __restrict__ WQ1,
                                               const float* __restrict__ WV1,
                                               int* __restrict__ off,
                                               int* __restrict__ tmap,
                                               ushort_t* __restrict__ QK0bf,
                                               ushort_t* __restrict__ Wfcbf,
                                               ushort_t* __restrict__ WV0bf,
                                               ushort_t* __restrict__ FCw0bf,
                                               ushort_t* __restrict__ WK1bf,
                                               ushort_t* __restrict__ WQ1Tbf,
                                               ushort_t* __restrict__ WV1bf) {
  int tid = threadIdx.x;
  __shared__ int toffs[65];
  if (tid < 64) {  // wave 0: scans for offsets and tile-offset prefix
    int len = xlens[tid];
    int v = len;
#pragma unroll
    for (int d = 1; d < 64; d <<= 1) {
      int t = __shfl_up(v, d);
      if (tid >= d) v += t;
    }
    off[tid + 1] = v;
    if (tid == 0) { off[0] = 0; toffs[0] = 0; }
    int nt = (len + 15) >> 4;
    int tv = nt;
#pragma unroll
    for (int d = 1; d < 64; d <<= 1) {
      int t = __shfl_up(tv, d);
      if (tid >= d) tv += t;
    }
    toffs[tid + 1] = tv;
    if (tid == 63) off[80] = tv;  // total tile count
  }
  __shared__ ushort_t Ibf[64][72];
  __shared__ ushort_t Wq0[64][72];
  __shared__ ushort_t Wk0T[64][72];
  __shared__ ushort_t qqbf[64][72];

  int w = tid >> 6, l = tid & 63, l15 = l & 15, lh = l >> 4;
  int srow = tid >> 2, sc0 = (tid & 3) << 4;
  int so = srow * 64 + sc0;

  cvt16(I + so, &Ibf[srow][sc0]);
  cvt16(WQ0 + so, &Wq0[srow][sc0]);
  {
    const float* s = WK0 + so;
#pragma unroll
    for (int i = 0; i < 16; ++i) Wk0T[sc0 + i][srow] = f2bf(s[i]);  // [e][a]
  }
  cvt16(FCw1 + so, Wfcbf + so);
  cvt16(WV0 + so, WV0bf + so);
  cvt16(FCw0 + so, FCw0bf + so);
  cvt16(WK1 + so, WK1bf + so);
  cvt16(WV1 + so, WV1bf + so);
  {
    const float* s = WQ1 + so;
#pragma unroll
    for (int i = 0; i < 16; ++i) WQ1Tbf[(sc0 + i) * 64 + srow] = f2bf(s[i]);  // [e][a]
  }
  __syncthreads();

  // ---- cooperative tmap fill (coalesced; ~36 iters/thread) ----
  {
    int ntiles = toffs[64];
    for (int i = tid; i < ntiles; i += 256) {
      int lo = 0, hi = 63;
      while (lo < hi) {
        int mid = (lo + hi + 1) >> 1;
        if (toffs[mid] <= i) lo = mid; else hi = mid - 1;
      }
      tmap[i] = (lo << 16) | (i - toffs[lo]);
    }
  }

  short8 ai0 = *(const short8*)&Ibf[16 * w + l15][lh * 8];
  short8 ai1 = *(const short8*)&Ibf[16 * w + l15][32 + lh * 8];
  f32x4 cA[4];
#pragma unroll
  for (int n = 0; n < 4; ++n) {
    short8 b0 = *(const short8*)&Wq0[16 * n + l15][lh * 8];
    short8 b1 = *(const short8*)&Wq0[16 * n + l15][32 + lh * 8];
    cA[n] = mm(ai0, b0, (f32x4){0.f, 0.f, 0.f, 0.f});
    cA[n] = mm(ai1, b1, cA[n]);
  }
#pragma unroll
  for (int n = 0; n < 4; ++n)
#pragma unroll
    for (int r = 0; r < 4; ++r)
      qqbf[16 * w + 4 * lh + r][16 * n + l15] = f2bf(cA[n][r]);  // own-wave rows

  short8 aq0 = *(const short8*)&qqbf[16 * w + l15][lh * 8];
  short8 aq1 = *(const short8*)&qqbf[16 * w + l15][32 + lh * 8];
  f32x4 cB[4];
#pragma unroll
  for (int n = 0; n < 4; ++n) {
    short8 b0 = *(const short8*)&Wk0T[16 * n + l15][lh * 8];
    short8 b1 = *(const short8*)&Wk0T[16 * n + l15][32 + lh * 8];
    cB[n] = mm(aq0, b0, (f32x4){0.f, 0.f, 0.f, 0.f});
    cB[n] = mm(aq1, b1, cB[n]);
  }
#pragma unroll
  for (int n = 0; n < 4; ++n)
#pragma unroll
    for (int r = 0; r < 4; ++r)
      QK0bf[(16 * w + 4 * lh + r) * 64 + 16 * n + l15] =
          f2bf(cB[n][r] * (ZINV * LOG2E));
}

// ---------------------------------------------------------------------------
// Phase A: per (segment, chunk) MFMA partials. No max subtraction (scores are
// O(0.1) by weight-scale construction). exp2 (log2e folded into QK0).
// ---------------------------------------------------------------------------
__global__ __launch_bounds__(256) void k_phaseA(const float* __restrict__ x,
                                                const int* __restrict__ off,
                                                const ushort_t* __restrict__ QK0bf,
                                                float* __restrict__ part_sm,
                                                float* __restrict__ part_ax) {
  int b = blockIdx.x / NCHUNK, chunk = blockIdx.x % NCHUNK;
  int s0 = off[b], L = off[b + 1] - s0;
  int clen = (L + NCHUNK - 1) / NCHUNK;
  int t0 = chunk * clen;
  int t1 = t0 + clen; if (t1 > L) t1 = L;

  __shared__ ushort_t xbf[64][72];  // [t][e]
  __shared__ ushort_t xT[64][72];   // [e][t]
  __shared__ ushort_t pbf[64][72];  // [m][t]

  int tid = threadIdx.x;
  int w = tid >> 6, l = tid & 63, l15 = l & 15, lh = l >> 4;
  int srow = tid >> 2, sc0 = (tid & 3) << 4;

  short8 aq0 = *(const short8*)(QK0bf + ((16 * w + l15) << 6) + lh * 8);
  short8 aq1 = *(const short8*)(QK0bf + ((16 * w + l15) << 6) + 32 + lh * 8);

  float sm[4] = {0.f, 0.f, 0.f, 0.f};
  f32x4 acc[4];
#pragma unroll
  for (int n = 0; n < 4; ++n) acc[n] = (f32x4){0.f, 0.f, 0.f, 0.f};

  float4 P0, P1, P2, P3;
  {
    int g = t0 + srow;
    int gc = g < t1 ? g : t1 - 1;
    const float4* src = (const float4*)(x + ((size_t)(s0 + gc) << 6) + sc0);
    P0 = src[0]; P1 = src[1]; P2 = src[2]; P3 = src[3];
  }

  for (int tt = t0; tt < t1; tt += 64) {
    __syncthreads();
    {
      float vv[16] = {P0.x, P0.y, P0.z, P0.w, P1.x, P1.y, P1.z, P1.w,
                      P2.x, P2.y, P2.z, P2.w, P3.x, P3.y, P3.z, P3.w};
      unsigned* dst = (unsigned*)&xbf[srow][sc0];
      dst[0] = pack2(vv[0], vv[1]);   dst[1] = pack2(vv[2], vv[3]);
      dst[2] = pack2(vv[4], vv[5]);   dst[3] = pack2(vv[6], vv[7]);
      dst[4] = pack2(vv[8], vv[9]);   dst[5] = pack2(vv[10], vv[11]);
      dst[6] = pack2(vv[12], vv[13]); dst[7] = pack2(vv[14], vv[15]);
#pragma unroll
      for (int i = 0; i < 16; ++i) xT[sc0 + i][srow] = f2bf(vv[i]);
    }
    __syncthreads();
    if (tt + 64 < t1) {
      int g = tt + 64 + srow;
      int gc = g < t1 ? g : t1 - 1;
      const float4* src = (const float4*)(x + ((size_t)(s0 + gc) << 6) + sc0);
      P0 = src[0]; P1 = src[1]; P2 = src[2]; P3 = src[3];
    }
    f32x4 c1[4];
#pragma unroll
    for (int n = 0; n < 4; ++n) {
      short8 bx0 = *(const short8*)&xbf[16 * n + l15][lh * 8];
      short8 bx1 = *(const short8*)&xbf[16 * n + l15][32 + lh * 8];
      c1[n] = mm(aq0, bx0, (f32x4){0.f, 0.f, 0.f, 0.f});
      c1[n] = mm(aq1, bx1, c1[n]);
    }
#pragma unroll
    for (int n = 0; n < 4; ++n) {
      bool v = (tt + 16 * n + l15) < t1;
#pragma unroll
      for (int r = 0; r < 4; ++r) {
        float pv = v ? exp2f(c1[n][r]) : 0.f;
        c1[n][r] = pv;
        sm[r] += pv;
      }
    }
#pragma unroll
    for (int n = 0; n < 4; ++n)
#pragma unroll
      for (int r = 0; r < 4; ++r)
        pbf[16 * w + 4 * lh + r][16 * n + l15] = f2bf(c1[n][r]);
    short8 pa0 = *(const short8*)&pbf[16 * w + l15][lh * 8];
    short8 pa1 = *(const short8*)&pbf[16 * w + l15][32 + lh * 8];
#pragma unroll
    for (int n = 0; n < 4; ++n) {
      short8 bt0 = *(const short8*)&xT[16 * n + l15][lh * 8];
      short8 bt1 = *(const short8*)&xT[16 * n + l15][32 + lh * 8];
      acc[n] = mm(pa0, bt0, acc[n]);
      acc[n] = mm(pa1, bt1, acc[n]);
    }
  }
  int base = (b * NCHUNK + chunk) * 64;
#pragma unroll
  for (int r = 0; r < 4; ++r) {
    sm[r] += __shfl_xor(sm[r], 1);
    sm[r] += __shfl_xor(sm[r], 2);
    sm[r] += __shfl_xor(sm[r], 4);
    sm[r] += __shfl_xor(sm[r], 8);
  }
  if (l15 == 0) {
#pragma unroll
    for (int r = 0; r < 4; ++r)
      part_sm[base + 16 * w + 4 * lh + r] = sm[r];
  }
#pragma unroll
  for (int n = 0; n < 4; ++n)
#pragma unroll
    for (int r = 0; r < 4; ++r) {
      int m = 16 * w + 4 * lh + r;
      part_ax[((size_t)(base + m) << 6) + 16 * n + l15] = acc[n][r];
    }
}

// ---------------------------------------------------------------------------
// Combine (MFMA): plain-sum merge -> 5 chained per-wave GEMMs -> K1fbf, V1Tbf
// K1fbf carries ZINV*LOG2E (phase B uses exp2).
// ---------------------------------------------------------------------------
__global__ __launch_bounds__(256) void k_combine(const float* __restrict__ part_sm,
                                                 const float* __restrict__ part_ax,
                                                 const float* __restrict__ I,
                                                 const ushort_t* __restrict__ WV0bf,
                                                 const ushort_t* __restrict__ FCw0bf,
                                                 const float* __restrict__ FCb0,
                                                 const float* __restrict__ g00,
                                                 const float* __restrict__ b00,
                                                 const float* __restrict__ g01,
                                                 const float* __restrict__ b01,
                                                 const ushort_t* __restrict__ WK1bf,
                                                 const ushort_t* __restrict__ WQ1Tbf,
                                                 const ushort_t* __restrict__ WV1bf,
                                                 ushort_t* __restrict__ K1fbf,
                                                 ushort_t* __restrict__ V1Tbf) {
  int b = blockIdx.x;
  int tid = threadIdx.x;
  int w = tid >> 6, l = tid & 63, l15 = l & 15, lh = l >> 4;

  __shared__ ushort_t av[64][72];
  __shared__ ushort_t sb[64][72];

  {
    int m = tid >> 2, dq = tid & 3, e0 = dq << 4;
    float S = 0.f;
    float ax[16];
#pragma unroll
    for (int i = 0; i < 16; ++i) ax[i] = 0.f;
#pragma unroll
    for (int c = 0; c < NCHUNK; ++c) {
      int pb = (b * NCHUNK + c) * 64 + m;
      S += part_sm[pb];
      const f32x4* pa = (const f32x4*)(part_ax + ((size_t)pb << 6) + e0);
#pragma unroll
      for (int qd = 0; qd < 4; ++qd) {
        f32x4 v = pa[qd];
#pragma unroll
        for (int j = 0; j < 4; ++j) ax[qd * 4 + j] += v[j];
      }
    }
    float invS = 1.f / S;
    unsigned* dst = (unsigned*)&av[m][e0];
#pragma unroll
    for (int i = 0; i < 8; ++i)
      dst[i] = pack2(ax[2 * i] * invS, ax[2 * i + 1] * invS);
  }
  __syncthreads();

  float p00[4], q00[4], p01[4], q01[4], fcb[4];
#pragma unroll
  for (int n = 0; n < 4; ++n) {
    int d = 16 * n + l15;
    p00[n] = g00[d]; q00[n] = b00[d];
    p01[n] = g01[d]; q01[n] = b01[d];
    fcb[n] = FCb0[d];
  }
  int row = 16 * w + 4 * lh;

  short8 a0 = *(const short8*)&av[16 * w + l15][lh * 8];
  short8 a1 = *(const short8*)&av[16 * w + l15][32 + lh * 8];
  f32x4 c1[4];
#pragma unroll
  for (int n = 0; n < 4; ++n) {
    short8 b0 = *(const short8*)(WV0bf + ((16 * n + l15) << 6) + lh * 8);
    short8 b1 = *(const short8*)(WV0bf + ((16 * n + l15) << 6) + 32 + lh * 8);
    c1[n] = mm(a0, b0, (f32x4){0.f, 0.f, 0.f, 0.f});
    c1[n] = mm(a1, b1, c1[n]);
  }
  float hh[4][4];
#pragma unroll
  for (int r = 0; r < 4; ++r) {
    float h[4];
#pragma unroll
    for (int n = 0; n < 4; ++n)
      h[n] = c1[n][r] + I[(row + r) * 64 + 16 * n + l15];
    float s1 = h[0] + h[1] + h[2] + h[3];
    s1 += __shfl_xor(s1, 1); s1 += __shfl_xor(s1, 2);
    s1 += __shfl_xor(s1, 4); s1 += __shfl_xor(s1, 8);
    float mean = s1 * 0.015625f;
    float s2 = 0.f;
#pragma unroll
    for (int n = 0; n < 4; ++n) { float c = h[n] - mean; s2 += c * c; }
    s2 += __shfl_xor(s2, 1); s2 += __shfl_xor(s2, 2);
    s2 += __shfl_xor(s2, 4); s2 += __shfl_xor(s2, 8);
    float rs = rsqrtf(s2 * 0.015625f + EPS);
#pragma unroll
    for (int n = 0; n < 4; ++n) {
      hh[n][r] = (h[n] - mean) * rs * p00[n] + q00[n];
      sb[row + r][16 * n + l15] = f2bf(hh[n][r]);
    }
  }
  short8 h0 = *(const short8*)&sb[16 * w + l15][lh * 8];
  short8 h1 = *(const short8*)&sb[16 * w + l15][32 + lh * 8];
  f32x4 c2[4];
#pragma unroll
  for (int n = 0; n < 4; ++n) {
    short8 b0 = *(const short8*)(FCw0bf + ((16 * n + l15) << 6) + lh * 8);
    short8 b1 = *(const short8*)(FCw0bf + ((16 * n + l15) << 6) + 32 + lh * 8);
    c2[n] = mm(h0, b0, (f32x4){0.f, 0.f, 0.f, 0.f});
    c2[n] = mm(h1, b1, c2[n]);
  }
#pragma unroll
  for (int r = 0; r < 4; ++r) {
    float u[4];
#pragma unroll
    for (int n = 0; n < 4; ++n)
      u[n] = hh[n][r] + fmaxf(c2[n][r] + fcb[n], 0.f);
    float s1 = u[0] + u[1] + u[2] + u[3];
    s1 += __shfl_xor(s1, 1); s1 += __shfl_xor(s1, 2);
    s1 += __shfl_xor(s1, 4); s1 += __shfl_xor(s1, 8);
    float mean = s1 * 0.015625f;
    float s2 = 0.f;
#pragma unroll
    for (int n = 0; n < 4; ++n) { float c = u[n] - mean; s2 += c * c; }
    s2 += __shfl_xor(s2, 1); s2 += __shfl_xor(s2, 2);
    s2 += __shfl_xor(s2, 4); s2 += __shfl_xor(s2, 8);
    float rs = rsqrtf(s2 * 0.015625f + EPS);
#pragma unroll
    for (int n = 0; n < 4; ++n)
      av[row + r][16 * n + l15] = f2bf((u[n] - mean) * rs * p01[n] + q01[n]);
  }
  short8 i0 = *(const short8*)&av[16 * w + l15][lh * 8];
  short8 i1 = *(const short8*)&av[16 * w + l15][32 + lh * 8];
  f32x4 c3[4];
#pragma unroll
  for (int n = 0; n < 4; ++n) {
    short8 b0 = *(const short8*)(WK1bf + ((16 * n + l15) << 6) + lh * 8);
    short8 b1 = *(const short8*)(WK1bf + ((16 * n + l15) << 6) + 32 + lh * 8);
    c3[n] = mm(i0, b0, (f32x4){0.f, 0.f, 0.f, 0.f});
    c3[n] = mm(i1, b1, c3[n]);
  }
#pragma unroll
  for (int n = 0; n < 4; ++n)
#pragma unroll
    for (int r = 0; r < 4; ++r)
      sb[row + r][16 * n + l15] = f2bf(c3[n][r]);
  short8 t0f = *(const short8*)&sb[16 * w + l15][lh * 8];
  short8 t1f = *(const short8*)&sb[16 * w + l15][32 + lh * 8];
  f32x4 c4[4];
#pragma unroll
  for (int n = 0; n < 4; ++n) {
    short8 b0 = *(const short8*)(WQ1Tbf + ((16 * n + l15) << 6) + lh * 8);
    short8 b1 = *(const short8*)(WQ1Tbf + ((16 * n + l15) << 6) + 32 + lh * 8);
    c4[n] = mm(t0f, b0, (f32x4){0.f, 0.f, 0.f, 0.f});
    c4[n] = mm(t1f, b1, c4[n]);
  }
#pragma unroll
  for (int n = 0; n < 4; ++n)
#pragma unroll
    for (int r = 0; r < 4; ++r)
      K1fbf[((size_t)(b * 64 + row + r) << 6) + 16 * n + l15] =
          f2bf(c4[n][r] * (ZINV * LOG2E));
  f32x4 c5[4];
#pragma unroll
  for (int n = 0; n < 4; ++n) {
    short8 b0 = *(const short8*)(WV1bf + ((16 * n + l15) << 6) + lh * 8);
    short8 b1 = *(const short8*)(WV1bf + ((16 * n + l15) << 6) + 32 + lh * 8);
    c5[n] = mm(i0, b0, (f32x4){0.f, 0.f, 0.f, 0.f});
    c5[n] = mm(i1, b1, c5[n]);
  }
#pragma unroll
  for (int n = 0; n < 4; ++n)
#pragma unroll
    for (int r = 0; r < 4; ++r)
      V1Tbf[((size_t)(b * 64 + 16 * n + l15) << 6) + row + r] = f2bf(c5[n][r]);
}

// ---------------------------------------------------------------------------
// Phase B (dense tile map): ONE WAVE PER BLOCK, one 16-token slice per block,
// grid sized to the REAL tile count. xs/pbf LDS union with sched fence.
// Zero barriers.
// ---------------------------------------------------------------------------
__global__ __launch_bounds__(64) void k_phaseB(const float* __restrict__ x,
                                               const int* __restrict__ off,
                                               const int* __restrict__ tmap,
                                               const ushort_t* __restrict__ K1fbf,
                                               const ushort_t* __restrict__ V1Tbf,
                                               const ushort_t* __restrict__ Wfcbf,
                                               const float* __restrict__ FCb1,
                                               const float* __restrict__ g10,
                                               const float* __restrict__ b10,
                                               const float* __restrict__ g11,
                                               const float* __restrict__ b11,
                                               float* __restrict__ outp) {
  int idx = blockIdx.x;
  if (idx >= off[80]) return;   // total tile count (scalar, L2-hot)
  int mp = tmap[idx];
  int b = mp >> 16, slice = mp & 0xffff;
  int s0 = off[b], L = off[b + 1] - s0;
  int t16 = slice << 4;  // first token of this 16-row slice (always < L)

  __shared__ char ldsbuf[16 * 68 * 4];              // 4352 B shared buffer
  float (*xs)[68] = (float(*)[68])ldsbuf;           // fp32 tile (phase 1)
  ushort_t (*pbf)[72] = (ushort_t(*)[72])ldsbuf;    // P/hh round-trip (phase 2)

  int tid = threadIdx.x;  // 0..63
  int l15 = tid & 15, lh = tid >> 4;

  float gg0[4], bb0[4], gg1[4], bb1[4], fb[4];
#pragma unroll
  for (int n = 0; n < 4; ++n) {
    int d = 16 * n + l15;
    gg0[n] = g10[d]; bb0[n] = b10[d];
    gg1[n] = g11[d]; bb1[n] = b11[d];
    fb[n] = FCb1[d];
  }
  const ushort_t* Kb = K1fbf + ((size_t)b << 12);
  const ushort_t* Vb = V1Tbf + ((size_t)b << 12);

  // ---- A-frag (row t16 + l15, clamped); wave collectively holds the tile ----
  int rA = t16 + l15; if (rA >= L) rA = L - 1;
  const float* xr = x + ((size_t)(s0 + rA) << 6);
  float4 xa0 = *(const float4*)(xr + lh * 8);
  float4 xa1 = *(const float4*)(xr + lh * 8 + 4);
  float4 xa2 = *(const float4*)(xr + 32 + lh * 8);
  float4 xa3 = *(const float4*)(xr + 32 + lh * 8 + 4);
  // ---- stage fp32 tile to LDS (2-way bank aliasing = free) ----
  *(float4*)&xs[l15][lh * 8] = xa0;
  *(float4*)&xs[l15][lh * 8 + 4] = xa1;
  *(float4*)&xs[l15][32 + lh * 8] = xa2;
  *(float4*)&xs[l15][32 + lh * 8 + 4] = xa3;
  // ---- GEMM1: scores ----
  short8 a0 = cvt8(xa0, xa1);
  short8 a1 = cvt8(xa2, xa3);
  f32x4 c1[4];
#pragma unroll
  for (int n = 0; n < 4; ++n) {
    short8 bk0 = *(const short8*)(Kb + ((16 * n + l15) << 6) + lh * 8);
    short8 bk1 = *(const short8*)(Kb + ((16 * n + l15) << 6) + 32 + lh * 8);
    c1[n] = mm(a0, bk0, (f32x4){0.f, 0.f, 0.f, 0.f});
    c1[n] = mm(a1, bk1, c1[n]);
  }
  // ---- residual from LDS (xs dead after this) ----
  float res[4][4];
#pragma unroll
  for (int r = 0; r < 4; ++r)
#pragma unroll
    for (int n = 0; n < 4; ++n)
      res[n][r] = xs[4 * lh + r][16 * n + l15];
  // compile-time fence: res ds_reads MUST precede aliased pbf ds_writes
  __builtin_amdgcn_sched_barrier(0);
  // ---- p = exp2(s), row-sum (no max chain) ----
  float inv[4];
#pragma unroll
  for (int r = 0; r < 4; ++r) {
    float s = 0.f;
#pragma unroll
    for (int n = 0; n < 4; ++n) {
      float p = exp2f(c1[n][r]);
      c1[n][r] = p;
      s += p;
    }
    s += __shfl_xor(s, 1);
    s += __shfl_xor(s, 2);
    s += __shfl_xor(s, 4);
    s += __shfl_xor(s, 8);
    inv[r] = 1.f / s;
  }
#pragma unroll
  for (int n = 0; n < 4; ++n)
#pragma unroll
    for (int r = 0; r < 4; ++r)
      pbf[4 * lh + r][16 * n + l15] = f2bf(c1[n][r]);
  short8 pa0 = *(const short8*)&pbf[l15][lh * 8];
  short8 pa1 = *(const short8*)&pbf[l15][32 + lh * 8];
  f32x4 c2[4];
#pragma unroll
  for (int n = 0; n < 4; ++n) {
    short8 bv0 = *(const short8*)(Vb + ((16 * n + l15) << 6) + lh * 8);
    short8 bv1 = *(const short8*)(Vb + ((16 * n + l15) << 6) + 32 + lh * 8);
    c2[n] = mm(pa0, bv0, (f32x4){0.f, 0.f, 0.f, 0.f});
    c2[n] = mm(pa1, bv1, c2[n]);
  }
  // ---- residual + LN1 -> hh -> pbf ----
  float hh[4][4];
#pragma unroll
  for (int r = 0; r < 4; ++r) {
    float h[4];
#pragma unroll
    for (int n = 0; n < 4; ++n)
      h[n] = c2[n][r] * inv[r] + res[n][r];
    float s1 = h[0] + h[1] + h[2] + h[3];
    s1 += __shfl_xor(s1, 1); s1 += __shfl_xor(s1, 2);
    s1 += __shfl_xor(s1, 4); s1 += __shfl_xor(s1, 8);
    float mean = s1 * 0.015625f;
    float s2 = 0.f;
#pragma unroll
    for (int n = 0; n < 4; ++n) { float c = h[n] - mean; s2 += c * c; }
    s2 += __shfl_xor(s2, 1); s2 += __shfl_xor(s2, 2);
    s2 += __shfl_xor(s2, 4); s2 += __shfl_xor(s2, 8);
    float rs = rsqrtf(s2 * 0.015625f + EPS);
#pragma unroll
    for (int n = 0; n < 4; ++n) {
      hh[n][r] = (h[n] - mean) * rs * gg0[n] + bb0[n];
      pbf[4 * lh + r][16 * n + l15] = f2bf(hh[n][r]);
    }
  }
  // ---- GEMM3: FC ----
  short8 ha0 = *(const short8*)&pbf[l15][lh * 8];
  short8 ha1 = *(const short8*)&pbf[l15][32 + lh * 8];
  f32x4 c3[4];
#pragma unroll
  for (int n = 0; n < 4; ++n) {
    short8 bw0 = *(const short8*)(Wfcbf + ((16 * n + l15) << 6) + lh * 8);
    short8 bw1 = *(const short8*)(Wfcbf + ((16 * n + l15) << 6) + 32 + lh * 8);
    c3[n] = mm(ha0, bw0, (f32x4){0.f, 0.f, 0.f, 0.f});
    c3[n] = mm(ha1, bw1, c3[n]);
  }
  // ---- relu + residual + LN2 + store ----
#pragma unroll
  for (int r = 0; r < 4; ++r) {
    int trow = t16 + 4 * lh + r;
    float u[4];
#pragma unroll
    for (int n = 0; n < 4; ++n)
      u[n] = hh[n][r] + fmaxf(c3[n][r] + fb[n], 0.f);
    float s1 = u[0] + u[1] + u[2] + u[3];
    s1 += __shfl_xor(s1, 1); s1 += __shfl_xor(s1, 2);
    s1 += __shfl_xor(s1, 4); s1 += __shfl_xor(s1, 8);
    float mean = s1 * 0.015625f;
    float s2 = 0.f;
#pragma unroll
    for (int n = 0; n < 4; ++n) { float c = u[n] - mean; s2 += c * c; }
    s2 += __shfl_xor(s2, 1); s2 += __shfl_xor(s2, 2);
    s2 += __shfl_xor(s2, 4); s2 += __shfl_xor(s2, 8);
    float rs = rsqrtf(s2 * 0.015625f + EPS);
    if (trow < L) {
#pragma unroll
      for (int n = 0; n < 4; ++n)
        outp[((size_t)(s0 + trow) << 6) + 16 * n + l15] =
            (u[n] - mean) * rs * gg1[n] + bb1[n];
    }
  }
}

// ---------------------------------------------------------------------------

extern "C" void kernel_launch(void* const* d_in, const int* in_sizes, int n_in,
                              void* d_out, int out_size, void* d_ws, size_t ws_size,
                              hipStream_t stream) {
  const float* x    = (const float*)d_in[0];
  const int*   xlen = (const int*)d_in[1];
  const float* I    = (const float*)d_in[2];
  const float* WQ0  = (const float*)d_in[3];
  const float* WK0  = (const float*)d_in[4];
  const float* WV0  = (const float*)d_in[5];
  const float* FCw0 = (const float*)d_in[6];
  const float* FCb0 = (const float*)d_in[7];
  const float* g00  = (const float*)d_in[8];
  const float* b00  = (const float*)d_in[9];
  const float* g01  = (const float*)d_in[10];
  const float* b01  = (const float*)d_in[11];
  const float* WQ1  = (const float*)d_in[12];
  const float* WK1  = (const float*)d_in[13];
  const float* WV1  = (const float*)d_in[14];
  const float* FCw1 = (const float*)d_in[15];
  const float* FCb1 = (const float*)d_in[16];
  const float* g10  = (const float*)d_in[17];
  const float* b10  = (const float*)d_in[18];
  const float* g11  = (const float*)d_in[19];
  const float* b11  = (const float*)d_in[20];

  char* p = (char*)d_ws;
  int* off = (int*)p;                p += 1024;   // off[0..64], off[80]=ntiles
  int* tmap = (int*)p;               p += 64 * 256 * 4;  // dense tile map
  ushort_t* QK0bf = (ushort_t*)p;    p += 64 * 64 * 2;
  ushort_t* Wfcbf = (ushort_t*)p;    p += 64 * 64 * 2;
  ushort_t* WV0bf = (ushort_t*)p;    p += 64 * 64 * 2;
  ushort_t* FCw0bf = (ushort_t*)p;   p += 64 * 64 * 2;
  ushort_t* WK1bf = (ushort_t*)p;    p += 64 * 64 * 2;
  ushort_t* WQ1Tbf = (ushort_t*)p;   p += 64 * 64 * 2;
  ushort_t* WV1bf = (ushort_t*)p;    p += 64 * 64 * 2;
  ushort_t* K1fbf = (ushort_t*)p;    p += (size_t)NB * 64 * 64 * 2;
  ushort_t* V1Tbf = (ushort_t*)p;    p += (size_t)NB * 64 * 64 * 2;
  float* psm = (float*)p;            p += (size_t)NB * NCHUNK * 64 * 4;
  float* pax = (float*)p;            // NB*NCHUNK*64*64 floats = 8 MB

  int total = in_sizes[0] >> 6;                 // total tokens
  int gridB = (total >> 4) + NB;                // >= sum(ceil(L/16))

  k_setup<<<1, 256, 0, stream>>>(xlen, I, WQ0, WK0, FCw1, WV0, FCw0, WK1, WQ1, WV1,
                                 off, tmap, QK0bf, Wfcbf, WV0bf, FCw0bf, WK1bf,
                                 WQ1Tbf, WV1bf);
  k_phaseA<<<NB * NCHUNK, 256, 0, stream>>>(x, off, QK0bf, psm, pax);
  k_combine<<<NB, 256, 0, stream>>>(psm, pax, I, WV0bf, FCw0bf, FCb0,
                                    g00, b00, g01, b01, WK1bf, WQ1Tbf, WV1bf,
                                    K1fbf, V1Tbf);
  k_phaseB<<<gridB, 64, 0, stream>>>(x, off, tmap, K1fbf, V1Tbf, Wfcbf, FCb1,
                                     g10, b10, g11, b11, (float*)d_out);
}

// Round 22
// 78.924 us; speedup vs baseline: 1.1939x; 1.1939x over previous
//
#include <hip/hip_runtime.h>

#define NB 64
#define NCHUNK 8
#define ZINV 0.125f
#define LOG2E 1.44269504088896f
#define EPS 1e-5f

typedef __attribute__((ext_vector_type(8))) short short8;
typedef __attribute__((ext_vector_type(4))) float f32x4;
typedef unsigned short ushort_t;

__device__ __forceinline__ f32x4 mm(short8 a, short8 b, f32x4 c) {
  return __builtin_amdgcn_mfma_f32_16x16x32_bf16(a, b, c, 0, 0, 0);
}
__device__ __forceinline__ ushort_t f2bf(float f) {
  unsigned u = __float_as_uint(f);
  u += 0x7fffu + ((u >> 16) & 1u);
  return (ushort_t)(u >> 16);
}
__device__ __forceinline__ unsigned pack2(float a, float b) {
  return (unsigned)f2bf(a) | ((unsigned)f2bf(b) << 16);
}
// 8 fp32 (two float4) -> short8 bf16 frag
__device__ __forceinline__ short8 cvt8(float4 a, float4 b) {
  union { unsigned u[4]; short8 s; } z;
  z.u[0] = pack2(a.x, a.y); z.u[1] = pack2(a.z, a.w);
  z.u[2] = pack2(b.x, b.y); z.u[3] = pack2(b.z, b.w);
  return z.s;
}
// convert 16 contiguous f32 -> 16 contiguous bf16 (both 16B-aligned)
__device__ __forceinline__ void cvt16(const float* __restrict__ src, ushort_t* dst) {
  const float4* s = (const float4*)src;
  unsigned* d = (unsigned*)dst;
  float4 A0 = s[0], A1 = s[1], A2 = s[2], A3 = s[3];
  d[0] = pack2(A0.x, A0.y); d[1] = pack2(A0.z, A0.w);
  d[2] = pack2(A1.x, A1.y); d[3] = pack2(A1.z, A1.w);
  d[4] = pack2(A2.x, A2.y); d[5] = pack2(A2.z, A2.w);
  d[6] = pack2(A3.x, A3.y); d[7] = pack2(A3.z, A3.w);
}

// ---------------------------------------------------------------------------
// Setup (1 block): offsets via wave-scan; bf16 weight tables; QK0 via 2 MFMAs.
// QK0bf carries ZINV*LOG2E so phases use native exp2.
// ---------------------------------------------------------------------------
__global__ __launch_bounds__(256) void k_setup(const int* __restrict__ xlens,
                                               const float* __restrict__ I,
                                               const float* __restrict__ WQ0,
                                               const float* __restrict__ WK0,
                                               const float* __restrict__ FCw1,
                                               const float* __restrict__ WV0,
                                               const float* __restrict__ FCw0,
                                               const float* __restrict__ WK1,
                                               const float* __restrict__ WQ1,
                                               const float* __restrict__ WV1,
                                               int* __restrict__ off,
                                               ushort_t* __restrict__ QK0bf,
                                               ushort_t* __restrict__ Wfcbf,
                                               ushort_t* __restrict__ WV0bf,
                                               ushort_t* __restrict__ FCw0bf,
                                               ushort_t* __restrict__ WK1bf,
                                               ushort_t* __restrict__ WQ1Tbf,
                                               ushort_t* __restrict__ WV1bf) {
  int tid = threadIdx.x;
  if (tid < 64) {  // wave 0: parallel inclusive scan of xlens
    int v = xlens[tid];
#pragma unroll
    for (int d = 1; d < 64; d <<= 1) {
      int t = __shfl_up(v, d);
      if (tid >= d) v += t;
    }
    off[tid + 1] = v;
    if (tid == 0) off[0] = 0;
  }
  __shared__ ushort_t Ibf[64][72];
  __shared__ ushort_t Wq0[64][72];
  __shared__ ushort_t Wk0T[64][72];
  __shared__ ushort_t qqbf[64][72];

  int w = tid >> 6, l = tid & 63, l15 = l & 15, lh = l >> 4;
  int srow = tid >> 2, sc0 = (tid & 3) << 4;
  int so = srow * 64 + sc0;

  cvt16(I + so, &Ibf[srow][sc0]);
  cvt16(WQ0 + so, &Wq0[srow][sc0]);
  {
    const float* s = WK0 + so;
#pragma unroll
    for (int i = 0; i < 16; ++i) Wk0T[sc0 + i][srow] = f2bf(s[i]);  // [e][a]
  }
  cvt16(FCw1 + so, Wfcbf + so);
  cvt16(WV0 + so, WV0bf + so);
  cvt16(FCw0 + so, FCw0bf + so);
  cvt16(WK1 + so, WK1bf + so);
  cvt16(WV1 + so, WV1bf + so);
  {
    const float* s = WQ1 + so;
#pragma unroll
    for (int i = 0; i < 16; ++i) WQ1Tbf[(sc0 + i) * 64 + srow] = f2bf(s[i]);  // [e][a]
  }
  __syncthreads();

  short8 ai0 = *(const short8*)&Ibf[16 * w + l15][lh * 8];
  short8 ai1 = *(const short8*)&Ibf[16 * w + l15][32 + lh * 8];
  f32x4 cA[4];
#pragma unroll
  for (int n = 0; n < 4; ++n) {
    short8 b0 = *(const short8*)&Wq0[16 * n + l15][lh * 8];
    short8 b1 = *(const short8*)&Wq0[16 * n + l15][32 + lh * 8];
    cA[n] = mm(ai0, b0, (f32x4){0.f, 0.f, 0.f, 0.f});
    cA[n] = mm(ai1, b1, cA[n]);
  }
#pragma unroll
  for (int n = 0; n < 4; ++n)
#pragma unroll
    for (int r = 0; r < 4; ++r)
      qqbf[16 * w + 4 * lh + r][16 * n + l15] = f2bf(cA[n][r]);  // own-wave rows

  short8 aq0 = *(const short8*)&qqbf[16 * w + l15][lh * 8];
  short8 aq1 = *(const short8*)&qqbf[16 * w + l15][32 + lh * 8];
  f32x4 cB[4];
#pragma unroll
  for (int n = 0; n < 4; ++n) {
    short8 b0 = *(const short8*)&Wk0T[16 * n + l15][lh * 8];
    short8 b1 = *(const short8*)&Wk0T[16 * n + l15][32 + lh * 8];
    cB[n] = mm(aq0, b0, (f32x4){0.f, 0.f, 0.f, 0.f});
    cB[n] = mm(aq1, b1, cB[n]);
  }
#pragma unroll
  for (int n = 0; n < 4; ++n)
#pragma unroll
    for (int r = 0; r < 4; ++r)
      QK0bf[(16 * w + 4 * lh + r) * 64 + 16 * n + l15] =
          f2bf(cB[n][r] * (ZINV * LOG2E));
}

// ---------------------------------------------------------------------------
// Phase A: per (segment, chunk) MFMA partials. No max subtraction (scores are
// O(0.1) by weight-scale construction). exp2 (log2e folded into QK0).
// ---------------------------------------------------------------------------
__global__ __launch_bounds__(256) void k_phaseA(const float* __restrict__ x,
                                                const int* __restrict__ off,
                                                const ushort_t* __restrict__ QK0bf,
                                                float* __restrict__ part_sm,
                                                float* __restrict__ part_ax) {
  int b = blockIdx.x / NCHUNK, chunk = blockIdx.x % NCHUNK;
  int s0 = off[b], L = off[b + 1] - s0;
  int clen = (L + NCHUNK - 1) / NCHUNK;
  int t0 = chunk * clen;
  int t1 = t0 + clen; if (t1 > L) t1 = L;

  __shared__ ushort_t xbf[64][72];  // [t][e]
  __shared__ ushort_t xT[64][72];   // [e][t]
  __shared__ ushort_t pbf[64][72];  // [m][t]

  int tid = threadIdx.x;
  int w = tid >> 6, l = tid & 63, l15 = l & 15, lh = l >> 4;
  int srow = tid >> 2, sc0 = (tid & 3) << 4;

  short8 aq0 = *(const short8*)(QK0bf + ((16 * w + l15) << 6) + lh * 8);
  short8 aq1 = *(const short8*)(QK0bf + ((16 * w + l15) << 6) + 32 + lh * 8);

  float sm[4] = {0.f, 0.f, 0.f, 0.f};
  f32x4 acc[4];
#pragma unroll
  for (int n = 0; n < 4; ++n) acc[n] = (f32x4){0.f, 0.f, 0.f, 0.f};

  float4 P0, P1, P2, P3;
  {
    int g = t0 + srow;
    int gc = g < t1 ? g : t1 - 1;
    const float4* src = (const float4*)(x + ((size_t)(s0 + gc) << 6) + sc0);
    P0 = src[0]; P1 = src[1]; P2 = src[2]; P3 = src[3];
  }

  for (int tt = t0; tt < t1; tt += 64) {
    __syncthreads();
    {
      float vv[16] = {P0.x, P0.y, P0.z, P0.w, P1.x, P1.y, P1.z, P1.w,
                      P2.x, P2.y, P2.z, P2.w, P3.x, P3.y, P3.z, P3.w};
      unsigned* dst = (unsigned*)&xbf[srow][sc0];
      dst[0] = pack2(vv[0], vv[1]);   dst[1] = pack2(vv[2], vv[3]);
      dst[2] = pack2(vv[4], vv[5]);   dst[3] = pack2(vv[6], vv[7]);
      dst[4] = pack2(vv[8], vv[9]);   dst[5] = pack2(vv[10], vv[11]);
      dst[6] = pack2(vv[12], vv[13]); dst[7] = pack2(vv[14], vv[15]);
#pragma unroll
      for (int i = 0; i < 16; ++i) xT[sc0 + i][srow] = f2bf(vv[i]);
    }
    __syncthreads();
    if (tt + 64 < t1) {
      int g = tt + 64 + srow;
      int gc = g < t1 ? g : t1 - 1;
      const float4* src = (const float4*)(x + ((size_t)(s0 + gc) << 6) + sc0);
      P0 = src[0]; P1 = src[1]; P2 = src[2]; P3 = src[3];
    }
    f32x4 c1[4];
#pragma unroll
    for (int n = 0; n < 4; ++n) {
      short8 bx0 = *(const short8*)&xbf[16 * n + l15][lh * 8];
      short8 bx1 = *(const short8*)&xbf[16 * n + l15][32 + lh * 8];
      c1[n] = mm(aq0, bx0, (f32x4){0.f, 0.f, 0.f, 0.f});
      c1[n] = mm(aq1, bx1, c1[n]);
    }
#pragma unroll
    for (int n = 0; n < 4; ++n) {
      bool v = (tt + 16 * n + l15) < t1;
#pragma unroll
      for (int r = 0; r < 4; ++r) {
        float pv = v ? exp2f(c1[n][r]) : 0.f;
        c1[n][r] = pv;
        sm[r] += pv;
      }
    }
#pragma unroll
    for (int n = 0; n < 4; ++n)
#pragma unroll
      for (int r = 0; r < 4; ++r)
        pbf[16 * w + 4 * lh + r][16 * n + l15] = f2bf(c1[n][r]);
    short8 pa0 = *(const short8*)&pbf[16 * w + l15][lh * 8];
    short8 pa1 = *(const short8*)&pbf[16 * w + l15][32 + lh * 8];
#pragma unroll
    for (int n = 0; n < 4; ++n) {
      short8 bt0 = *(const short8*)&xT[16 * n + l15][lh * 8];
      short8 bt1 = *(const short8*)&xT[16 * n + l15][32 + lh * 8];
      acc[n] = mm(pa0, bt0, acc[n]);
      acc[n] = mm(pa1, bt1, acc[n]);
    }
  }
  int base = (b * NCHUNK + chunk) * 64;
#pragma unroll
  for (int r = 0; r < 4; ++r) {
    sm[r] += __shfl_xor(sm[r], 1);
    sm[r] += __shfl_xor(sm[r], 2);
    sm[r] += __shfl_xor(sm[r], 4);
    sm[r] += __shfl_xor(sm[r], 8);
  }
  if (l15 == 0) {
#pragma unroll
    for (int r = 0; r < 4; ++r)
      part_sm[base + 16 * w + 4 * lh + r] = sm[r];
  }
#pragma unroll
  for (int n = 0; n < 4; ++n)
#pragma unroll
    for (int r = 0; r < 4; ++r) {
      int m = 16 * w + 4 * lh + r;
      part_ax[((size_t)(base + m) << 6) + 16 * n + l15] = acc[n][r];
    }
}

// ---------------------------------------------------------------------------
// Combine (MFMA): plain-sum merge -> 5 chained per-wave GEMMs -> K1fbf, V1Tbf
// K1fbf carries ZINV*LOG2E (phase B uses exp2).
// ---------------------------------------------------------------------------
__global__ __launch_bounds__(256) void k_combine(const float* __restrict__ part_sm,
                                                 const float* __restrict__ part_ax,
                                                 const float* __restrict__ I,
                                                 const ushort_t* __restrict__ WV0bf,
                                                 const ushort_t* __restrict__ FCw0bf,
                                                 const float* __restrict__ FCb0,
                                                 const float* __restrict__ g00,
                                                 const float* __restrict__ b00,
                                                 const float* __restrict__ g01,
                                                 const float* __restrict__ b01,
                                                 const ushort_t* __restrict__ WK1bf,
                                                 const ushort_t* __restrict__ WQ1Tbf,
                                                 const ushort_t* __restrict__ WV1bf,
                                                 ushort_t* __restrict__ K1fbf,
                                                 ushort_t* __restrict__ V1Tbf) {
  int b = blockIdx.x;
  int tid = threadIdx.x;
  int w = tid >> 6, l = tid & 63, l15 = l & 15, lh = l >> 4;

  __shared__ ushort_t av[64][72];
  __shared__ ushort_t sb[64][72];

  {
    int m = tid >> 2, dq = tid & 3, e0 = dq << 4;
    float S = 0.f;
    float ax[16];
#pragma unroll
    for (int i = 0; i < 16; ++i) ax[i] = 0.f;
#pragma unroll
    for (int c = 0; c < NCHUNK; ++c) {
      int pb = (b * NCHUNK + c) * 64 + m;
      S += part_sm[pb];
      const f32x4* pa = (const f32x4*)(part_ax + ((size_t)pb << 6) + e0);
#pragma unroll
      for (int qd = 0; qd < 4; ++qd) {
        f32x4 v = pa[qd];
#pragma unroll
        for (int j = 0; j < 4; ++j) ax[qd * 4 + j] += v[j];
      }
    }
    float invS = 1.f / S;
    unsigned* dst = (unsigned*)&av[m][e0];
#pragma unroll
    for (int i = 0; i < 8; ++i)
      dst[i] = pack2(ax[2 * i] * invS, ax[2 * i + 1] * invS);
  }
  __syncthreads();

  float p00[4], q00[4], p01[4], q01[4], fcb[4];
#pragma unroll
  for (int n = 0; n < 4; ++n) {
    int d = 16 * n + l15;
    p00[n] = g00[d]; q00[n] = b00[d];
    p01[n] = g01[d]; q01[n] = b01[d];
    fcb[n] = FCb0[d];
  }
  int row = 16 * w + 4 * lh;

  short8 a0 = *(const short8*)&av[16 * w + l15][lh * 8];
  short8 a1 = *(const short8*)&av[16 * w + l15][32 + lh * 8];
  f32x4 c1[4];
#pragma unroll
  for (int n = 0; n < 4; ++n) {
    short8 b0 = *(const short8*)(WV0bf + ((16 * n + l15) << 6) + lh * 8);
    short8 b1 = *(const short8*)(WV0bf + ((16 * n + l15) << 6) + 32 + lh * 8);
    c1[n] = mm(a0, b0, (f32x4){0.f, 0.f, 0.f, 0.f});
    c1[n] = mm(a1, b1, c1[n]);
  }
  float hh[4][4];
#pragma unroll
  for (int r = 0; r < 4; ++r) {
    float h[4];
#pragma unroll
    for (int n = 0; n < 4; ++n)
      h[n] = c1[n][r] + I[(row + r) * 64 + 16 * n + l15];
    float s1 = h[0] + h[1] + h[2] + h[3];
    s1 += __shfl_xor(s1, 1); s1 += __shfl_xor(s1, 2);
    s1 += __shfl_xor(s1, 4); s1 += __shfl_xor(s1, 8);
    float mean = s1 * 0.015625f;
    float s2 = 0.f;
#pragma unroll
    for (int n = 0; n < 4; ++n) { float c = h[n] - mean; s2 += c * c; }
    s2 += __shfl_xor(s2, 1); s2 += __shfl_xor(s2, 2);
    s2 += __shfl_xor(s2, 4); s2 += __shfl_xor(s2, 8);
    float rs = rsqrtf(s2 * 0.015625f + EPS);
#pragma unroll
    for (int n = 0; n < 4; ++n) {
      hh[n][r] = (h[n] - mean) * rs * p00[n] + q00[n];
      sb[row + r][16 * n + l15] = f2bf(hh[n][r]);
    }
  }
  short8 h0 = *(const short8*)&sb[16 * w + l15][lh * 8];
  short8 h1 = *(const short8*)&sb[16 * w + l15][32 + lh * 8];
  f32x4 c2[4];
#pragma unroll
  for (int n = 0; n < 4; ++n) {
    short8 b0 = *(const short8*)(FCw0bf + ((16 * n + l15) << 6) + lh * 8);
    short8 b1 = *(const short8*)(FCw0bf + ((16 * n + l15) << 6) + 32 + lh * 8);
    c2[n] = mm(h0, b0, (f32x4){0.f, 0.f, 0.f, 0.f});
    c2[n] = mm(h1, b1, c2[n]);
  }
#pragma unroll
  for (int r = 0; r < 4; ++r) {
    float u[4];
#pragma unroll
    for (int n = 0; n < 4; ++n)
      u[n] = hh[n][r] + fmaxf(c2[n][r] + fcb[n], 0.f);
    float s1 = u[0] + u[1] + u[2] + u[3];
    s1 += __shfl_xor(s1, 1); s1 += __shfl_xor(s1, 2);
    s1 += __shfl_xor(s1, 4); s1 += __shfl_xor(s1, 8);
    float mean = s1 * 0.015625f;
    float s2 = 0.f;
#pragma unroll
    for (int n = 0; n < 4; ++n) { float c = u[n] - mean; s2 += c * c; }
    s2 += __shfl_xor(s2, 1); s2 += __shfl_xor(s2, 2);
    s2 += __shfl_xor(s2, 4); s2 += __shfl_xor(s2, 8);
    float rs = rsqrtf(s2 * 0.015625f + EPS);
#pragma unroll
    for (int n = 0; n < 4; ++n)
      av[row + r][16 * n + l15] = f2bf((u[n] - mean) * rs * p01[n] + q01[n]);
  }
  short8 i0 = *(const short8*)&av[16 * w + l15][lh * 8];
  short8 i1 = *(const short8*)&av[16 * w + l15][32 + lh * 8];
  f32x4 c3[4];
#pragma unroll
  for (int n = 0; n < 4; ++n) {
    short8 b0 = *(const short8*)(WK1bf + ((16 * n + l15) << 6) + lh * 8);
    short8 b1 = *(const short8*)(WK1bf + ((16 * n + l15) << 6) + 32 + lh * 8);
    c3[n] = mm(i0, b0, (f32x4){0.f, 0.f, 0.f, 0.f});
    c3[n] = mm(i1, b1, c3[n]);
  }
#pragma unroll
  for (int n = 0; n < 4; ++n)
#pragma unroll
    for (int r = 0; r < 4; ++r)
      sb[row + r][16 * n + l15] = f2bf(c3[n][r]);
  short8 t0f = *(const short8*)&sb[16 * w + l15][lh * 8];
  short8 t1f = *(const short8*)&sb[16 * w + l15][32 + lh * 8];
  f32x4 c4[4];
#pragma unroll
  for (int n = 0; n < 4; ++n) {
    short8 b0 = *(const short8*)(WQ1Tbf + ((16 * n + l15) << 6) + lh * 8);
    short8 b1 = *(const short8*)(WQ1Tbf + ((16 * n + l15) << 6) + 32 + lh * 8);
    c4[n] = mm(t0f, b0, (f32x4){0.f, 0.f, 0.f, 0.f});
    c4[n] = mm(t1f, b1, c4[n]);
  }
#pragma unroll
  for (int n = 0; n < 4; ++n)
#pragma unroll
    for (int r = 0; r < 4; ++r)
      K1fbf[((size_t)(b * 64 + row + r) << 6) + 16 * n + l15] =
          f2bf(c4[n][r] * (ZINV * LOG2E));
  f32x4 c5[4];
#pragma unroll
  for (int n = 0; n < 4; ++n) {
    short8 b0 = *(const short8*)(WV1bf + ((16 * n + l15) << 6) + lh * 8);
    short8 b1 = *(const short8*)(WV1bf + ((16 * n + l15) << 6) + 32 + lh * 8);
    c5[n] = mm(i0, b0, (f32x4){0.f, 0.f, 0.f, 0.f});
    c5[n] = mm(i1, b1, c5[n]);
  }
#pragma unroll
  for (int n = 0; n < 4; ++n)
#pragma unroll
    for (int r = 0; r < 4; ++r)
      V1Tbf[((size_t)(b * 64 + 16 * n + l15) << 6) + row + r] = f2bf(c5[n][r]);
}

// ---------------------------------------------------------------------------
// Phase B (final): ONE WAVE PER BLOCK, one 16-token slice. xs (fp32 tile) is
// dead after residual extraction; pbf ALIASES it (LDS 4.6 KB). sched fence
// pins the res ds_reads before the aliased pbf ds_writes. Zero barriers.
// ---------------------------------------------------------------------------
__global__ __launch_bounds__(64) void k_phaseB(const float* __restrict__ x,
                                               const int* __restrict__ off,
                                               const ushort_t* __restrict__ K1fbf,
                                               const ushort_t* __restrict__ V1Tbf,
                                               const ushort_t* __restrict__ Wfcbf,
                                               const float* __restrict__ FCb1,
                                               const float* __restrict__ g10,
                                               const float* __restrict__ b10,
                                               const float* __restrict__ g11,
                                               const float* __restrict__ b11,
                                               float* __restrict__ outp) {
  int b = blockIdx.x >> 8, slice = blockIdx.x & 255;
  int s0 = off[b], L = off[b + 1] - s0;
  int t16 = slice << 4;  // first token of this 16-row slice
  if (t16 >= L) return;

  __shared__ char ldsbuf[16 * 68 * 4];              // 4352 B shared buffer
  float (*xs)[68] = (float(*)[68])ldsbuf;           // fp32 tile (phase 1)
  ushort_t (*pbf)[72] = (ushort_t(*)[72])ldsbuf;    // P/hh round-trip (phase 2)

  int tid = threadIdx.x;  // 0..63
  int l15 = tid & 15, lh = tid >> 4;

  float gg0[4], bb0[4], gg1[4], bb1[4], fb[4];
#pragma unroll
  for (int n = 0; n < 4; ++n) {
    int d = 16 * n + l15;
    gg0[n] = g10[d]; bb0[n] = b10[d];
    gg1[n] = g11[d]; bb1[n] = b11[d];
    fb[n] = FCb1[d];
  }
  const ushort_t* Kb = K1fbf + ((size_t)b << 12);
  const ushort_t* Vb = V1Tbf + ((size_t)b << 12);

  // ---- A-frag (row t16 + l15, clamped); wave collectively holds the tile ----
  int rA = t16 + l15; if (rA >= L) rA = L - 1;
  const float* xr = x + ((size_t)(s0 + rA) << 6);
  float4 xa0 = *(const float4*)(xr + lh * 8);
  float4 xa1 = *(const float4*)(xr + lh * 8 + 4);
  float4 xa2 = *(const float4*)(xr + 32 + lh * 8);
  float4 xa3 = *(const float4*)(xr + 32 + lh * 8 + 4);
  // ---- stage fp32 tile to LDS (2-way bank aliasing = free) ----
  *(float4*)&xs[l15][lh * 8] = xa0;
  *(float4*)&xs[l15][lh * 8 + 4] = xa1;
  *(float4*)&xs[l15][32 + lh * 8] = xa2;
  *(float4*)&xs[l15][32 + lh * 8 + 4] = xa3;
  // ---- GEMM1: scores ----
  short8 a0 = cvt8(xa0, xa1);
  short8 a1 = cvt8(xa2, xa3);
  f32x4 c1[4];
#pragma unroll
  for (int n = 0; n < 4; ++n) {
    short8 bk0 = *(const short8*)(Kb + ((16 * n + l15) << 6) + lh * 8);
    short8 bk1 = *(const short8*)(Kb + ((16 * n + l15) << 6) + 32 + lh * 8);
    c1[n] = mm(a0, bk0, (f32x4){0.f, 0.f, 0.f, 0.f});
    c1[n] = mm(a1, bk1, c1[n]);
  }
  // ---- residual from LDS (xs dead after this) ----
  float res[4][4];
#pragma unroll
  for (int r = 0; r < 4; ++r)
#pragma unroll
    for (int n = 0; n < 4; ++n)
      res[n][r] = xs[4 * lh + r][16 * n + l15];
  // compile-time fence: res ds_reads MUST precede aliased pbf ds_writes
  __builtin_amdgcn_sched_barrier(0);
  // ---- p = exp2(s), row-sum (no max chain) ----
  float inv[4];
#pragma unroll
  for (int r = 0; r < 4; ++r) {
    float s = 0.f;
#pragma unroll
    for (int n = 0; n < 4; ++n) {
      float p = exp2f(c1[n][r]);
      c1[n][r] = p;
      s += p;
    }
    s += __shfl_xor(s, 1);
    s += __shfl_xor(s, 2);
    s += __shfl_xor(s, 4);
    s += __shfl_xor(s, 8);
    inv[r] = 1.f / s;
  }
#pragma unroll
  for (int n = 0; n < 4; ++n)
#pragma unroll
    for (int r = 0; r < 4; ++r)
      pbf[4 * lh + r][16 * n + l15] = f2bf(c1[n][r]);
  short8 pa0 = *(const short8*)&pbf[l15][lh * 8];
  short8 pa1 = *(const short8*)&pbf[l15][32 + lh * 8];
  f32x4 c2[4];
#pragma unroll
  for (int n = 0; n < 4; ++n) {
    short8 bv0 = *(const short8*)(Vb + ((16 * n + l15) << 6) + lh * 8);
    short8 bv1 = *(const short8*)(Vb + ((16 * n + l15) << 6) + 32 + lh * 8);
    c2[n] = mm(pa0, bv0, (f32x4){0.f, 0.f, 0.f, 0.f});
    c2[n] = mm(pa1, bv1, c2[n]);
  }
  // ---- residual + LN1 -> hh -> pbf ----
  float hh[4][4];
#pragma unroll
  for (int r = 0; r < 4; ++r) {
    float h[4];
#pragma unroll
    for (int n = 0; n < 4; ++n)
      h[n] = c2[n][r] * inv[r] + res[n][r];
    float s1 = h[0] + h[1] + h[2] + h[3];
    s1 += __shfl_xor(s1, 1); s1 += __shfl_xor(s1, 2);
    s1 += __shfl_xor(s1, 4); s1 += __shfl_xor(s1, 8);
    float mean = s1 * 0.015625f;
    float s2 = 0.f;
#pragma unroll
    for (int n = 0; n < 4; ++n) { float c = h[n] - mean; s2 += c * c; }
    s2 += __shfl_xor(s2, 1); s2 += __shfl_xor(s2, 2);
    s2 += __shfl_xor(s2, 4); s2 += __shfl_xor(s2, 8);
    float rs = rsqrtf(s2 * 0.015625f + EPS);
#pragma unroll
    for (int n = 0; n < 4; ++n) {
      hh[n][r] = (h[n] - mean) * rs * gg0[n] + bb0[n];
      pbf[4 * lh + r][16 * n + l15] = f2bf(hh[n][r]);
    }
  }
  // ---- GEMM3: FC ----
  short8 ha0 = *(const short8*)&pbf[l15][lh * 8];
  short8 ha1 = *(const short8*)&pbf[l15][32 + lh * 8];
  f32x4 c3[4];
#pragma unroll
  for (int n = 0; n < 4; ++n) {
    short8 bw0 = *(const short8*)(Wfcbf + ((16 * n + l15) << 6) + lh * 8);
    short8 bw1 = *(const short8*)(Wfcbf + ((16 * n + l15) << 6) + 32 + lh * 8);
    c3[n] = mm(ha0, bw0, (f32x4){0.f, 0.f, 0.f, 0.f});
    c3[n] = mm(ha1, bw1, c3[n]);
  }
  // ---- relu + residual + LN2 + store ----
#pragma unroll
  for (int r = 0; r < 4; ++r) {
    int trow = t16 + 4 * lh + r;
    float u[4];
#pragma unroll
    for (int n = 0; n < 4; ++n)
      u[n] = hh[n][r] + fmaxf(c3[n][r] + fb[n], 0.f);
    float s1 = u[0] + u[1] + u[2] + u[3];
    s1 += __shfl_xor(s1, 1); s1 += __shfl_xor(s1, 2);
    s1 += __shfl_xor(s1, 4); s1 += __shfl_xor(s1, 8);
    float mean = s1 * 0.015625f;
    float s2 = 0.f;
#pragma unroll
    for (int n = 0; n < 4; ++n) { float c = u[n] - mean; s2 += c * c; }
    s2 += __shfl_xor(s2, 1); s2 += __shfl_xor(s2, 2);
    s2 += __shfl_xor(s2, 4); s2 += __shfl_xor(s2, 8);
    float rs = rsqrtf(s2 * 0.015625f + EPS);
    if (trow < L) {
#pragma unroll
      for (int n = 0; n < 4; ++n)
        outp[((size_t)(s0 + trow) << 6) + 16 * n + l15] =
            (u[n] - mean) * rs * gg1[n] + bb1[n];
    }
  }
}

// ---------------------------------------------------------------------------

extern "C" void kernel_launch(void* const* d_in, const int* in_sizes, int n_in,
                              void* d_out, int out_size, void* d_ws, size_t ws_size,
                              hipStream_t stream) {
  const float* x    = (const float*)d_in[0];
  const int*   xlen = (const int*)d_in[1];
  const float* I    = (const float*)d_in[2];
  const float* WQ0  = (const float*)d_in[3];
  const float* WK0  = (const float*)d_in[4];
  const float* WV0  = (const float*)d_in[5];
  const float* FCw0 = (const float*)d_in[6];
  const float* FCb0 = (const float*)d_in[7];
  const float* g00  = (const float*)d_in[8];
  const float* b00  = (const float*)d_in[9];
  const float* g01  = (const float*)d_in[10];
  const float* b01  = (const float*)d_in[11];
  const float* WQ1  = (const float*)d_in[12];
  const float* WK1  = (const float*)d_in[13];
  const float* WV1  = (const float*)d_in[14];
  const float* FCw1 = (const float*)d_in[15];
  const float* FCb1 = (const float*)d_in[16];
  const float* g10  = (const float*)d_in[17];
  const float* b10  = (const float*)d_in[18];
  const float* g11  = (const float*)d_in[19];
  const float* b11  = (const float*)d_in[20];

  char* p = (char*)d_ws;
  int* off = (int*)p;                p += 1024;
  ushort_t* QK0bf = (ushort_t*)p;    p += 64 * 64 * 2;
  ushort_t* Wfcbf = (ushort_t*)p;    p += 64 * 64 * 2;
  ushort_t* WV0bf = (ushort_t*)p;    p += 64 * 64 * 2;
  ushort_t* FCw0bf = (ushort_t*)p;   p += 64 * 64 * 2;
  ushort_t* WK1bf = (ushort_t*)p;    p += 64 * 64 * 2;
  ushort_t* WQ1Tbf = (ushort_t*)p;   p += 64 * 64 * 2;
  ushort_t* WV1bf = (ushort_t*)p;    p += 64 * 64 * 2;
  ushort_t* K1fbf = (ushort_t*)p;    p += (size_t)NB * 64 * 64 * 2;
  ushort_t* V1Tbf = (ushort_t*)p;    p += (size_t)NB * 64 * 64 * 2;
  float* psm = (float*)p;            p += (size_t)NB * NCHUNK * 64 * 4;
  float* pax = (float*)p;            // NB*NCHUNK*64*64 floats = 8 MB

  k_setup<<<1, 256, 0, stream>>>(xlen, I, WQ0, WK0, FCw1, WV0, FCw0, WK1, WQ1, WV1,
                                 off, QK0bf, Wfcbf, WV0bf, FCw0bf, WK1bf, WQ1Tbf, WV1bf);
  k_phaseA<<<NB * NCHUNK, 256, 0, stream>>>(x, off, QK0bf, psm, pax);
  k_combine<<<NB, 256, 0, stream>>>(psm, pax, I, WV0bf, FCw0bf, FCb0,
                                    g00, b00, g01, b01, WK1bf, WQ1Tbf, WV1bf,
                                    K1fbf, V1Tbf);
  k_phaseB<<<NB * 256, 64, 0, stream>>>(x, off, K1fbf, V1Tbf, Wfcbf, FCb1,
                                        g10, b10, g11, b11, (float*)d_out);
}